// Round 11
// baseline (638.361 us; speedup 1.0000x reference)
//
#include <hip/hip_runtime.h>
#include <hip/hip_bf16.h>
#include <math.h>

#define cN0 200000
#define cN1 50000
#define cN2 10000
#define cL  10
#define cE0 800000
#define cE1 160000
#define cV  100000
#define cIN 128
#define cH  256
#define cU  32
#define cLP 128

// fused-grid layout constants
#define PREP_CVT   18750              // (cV*cIN + cN0*cU)/1024
#define PREP_CNT   22500              // + (cE0+cE1)/256 = 3750
#define PREP_W0    22628              // + 128
#define PREP_TOT   22693              // + 65
#define MID_MAIN   54272              // 53 * 1024
#define MID_TOT    54774              // 1024 edge + 3750 scatter + 50000 embed
#define TAIL_TOT   1296               // 784 linear0 + 512 edge1

typedef __attribute__((ext_vector_type(8))) short short8;
typedef __attribute__((ext_vector_type(4))) float floatx4;

__device__ __forceinline__ float wave_sum(float v) {
#pragma unroll
    for (int m = 1; m < 64; m <<= 1) v += __shfl_xor(v, m);
    return v;
}

__device__ __forceinline__ float red16(float v) {
    v += __shfl_xor(v, 1); v += __shfl_xor(v, 2);
    v += __shfl_xor(v, 4); v += __shfl_xor(v, 8);
    return v;
}

__device__ __forceinline__ unsigned short bf16_rne(float f) {
    union { float f; unsigned u; } c; c.f = f;
    unsigned r = (c.u + 0x7FFFu + ((c.u >> 16) & 1u)) >> 16;
    return (unsigned short)r;
}

__device__ __forceinline__ float b2f(unsigned short u) {
    union { unsigned u; float f; } c; c.u = ((unsigned)u) << 16;
    return c.f;
}

__device__ __forceinline__ unsigned pkbf16(float a, float b) {
    union { __hip_bfloat162 h; unsigned u; } c;
    c.h = __float22bfloat162_rn(make_float2(a, b));
    return c.u;
}

__device__ __forceinline__ float2 unpk(unsigned p) {
    union { unsigned u; float f; } lo, hi;
    lo.u = p << 16; hi.u = p & 0xFFFF0000u;
    return make_float2(lo.f, hi.f);
}

// ================= edge MLP body (LDS weights, pipelined gather) =================
__device__ __forceinline__ void edge_mlp_body(
    ushort* WtL, float* par, int tid,
    const ushort* __restrict__ uni, int stride_i,
    const ushort* __restrict__ unj, int stride_j,
    const int* __restrict__ src, const int* __restrict__ dst, int E,
    const float* __restrict__ w1, const float* __restrict__ b1v,
    const float* __restrict__ gv, const float* __restrict__ bnv,
    const float* __restrict__ w2, const float* __restrict__ b2,
    float* __restrict__ A, int wid, int nw)
{
    int lane = tid & 63;
    int n = lane & 15, q = lane >> 4;
    if (tid < cLP) {
        par[tid * 4 + 0] = b1v[tid];
        par[tid * 4 + 1] = gv[tid];
        par[tid * 4 + 2] = bnv[tid];
        par[tid * 4 + 3] = w2[tid];
    }
    if (tid < 64) {
#pragma unroll
        for (int nt = 0; nt < 8; ++nt) {
#pragma unroll
            for (int c = 0; c < 3; ++c) {
                const float* p = &w1[(size_t)(16 * nt + n) * 96 + 32 * c + 8 * q];
                float4 v0 = *(const float4*)p;
                float4 v1 = *(const float4*)(p + 4);
                unsigned* dstw = (unsigned*)&WtL[(nt * 3 + c) * 512 + lane * 8];
                dstw[0] = pkbf16(v0.x, v0.y);
                dstw[1] = pkbf16(v0.z, v0.w);
                dstw[2] = pkbf16(v1.x, v1.y);
                dstw[3] = pkbf16(v1.z, v1.w);
            }
        }
    }
    __syncthreads();
    float b2s = b2[0];
    int ngroups = E >> 4;
    int g = wid;
    uint4 iv = {0, 0, 0, 0}, jv = {0, 0, 0, 0};
    if (g < ngroups) {
        int e = (g << 4) + n;
        int di = dst[e], si = src[e];
        iv = *(const uint4*)&uni[(size_t)di * stride_i + 8 * q];
        jv = *(const uint4*)&unj[(size_t)si * stride_j + 8 * q];
    }
    while (g < ngroups) {
        int gn = g + nw;
        int din = 0, sin = 0;
        if (gn < ngroups) {
            int e2 = (gn << 4) + n;
            din = dst[e2]; sin = src[e2];
        }
        union { short8 s; unsigned u[4]; } a0, a1, a2;
        {
            unsigned iw[4] = {iv.x, iv.y, iv.z, iv.w};
            unsigned jw[4] = {jv.x, jv.y, jv.z, jv.w};
#pragma unroll
            for (int d = 0; d < 4; ++d) {
                float2 u = unpk(iw[d]);
                float2 v = unpk(jw[d]);
                a0.u[d] = pkbf16(fabsf(u.x - v.x), fabsf(u.y - v.y));
                a1.u[d] = pkbf16(u.x + v.x, u.y + v.y);
                a2.u[d] = pkbf16(u.x * v.x, u.y * v.y);
            }
        }
        if (gn < ngroups) {
            iv = *(const uint4*)&uni[(size_t)din * stride_i + 8 * q];
            jv = *(const uint4*)&unj[(size_t)sin * stride_j + 8 * q];
        }
        floatx4 acc[8];
#pragma unroll
        for (int nt = 0; nt < 8; ++nt) acc[nt] = (floatx4){0.f, 0.f, 0.f, 0.f};
#pragma unroll
        for (int nt = 0; nt < 8; ++nt) {
            short8 b0 = *(const short8*)&WtL[(nt * 3 + 0) * 512 + lane * 8];
            short8 b1 = *(const short8*)&WtL[(nt * 3 + 1) * 512 + lane * 8];
            short8 b2w = *(const short8*)&WtL[(nt * 3 + 2) * 512 + lane * 8];
            acc[nt] = __builtin_amdgcn_mfma_f32_16x16x32_bf16(a0.s, b0, acc[nt], 0, 0, 0);
            acc[nt] = __builtin_amdgcn_mfma_f32_16x16x32_bf16(a1.s, b1, acc[nt], 0, 0, 0);
            acc[nt] = __builtin_amdgcn_mfma_f32_16x16x32_bf16(a2.s, b2w, acc[nt], 0, 0, 0);
        }
        float s1[4] = {0.f, 0.f, 0.f, 0.f}, s2[4] = {0.f, 0.f, 0.f, 0.f};
#pragma unroll
        for (int nt = 0; nt < 8; ++nt) {
            float4 pp = *(const float4*)&par[(16 * nt + n) * 4];
#pragma unroll
            for (int r = 0; r < 4; ++r) {
                float h = acc[nt][r] + pp.x;
                acc[nt][r] = h;
                s1[r] += h; s2[r] = fmaf(h, h, s2[r]);
            }
        }
        float rstd[4], mrr[4];
#pragma unroll
        for (int r = 0; r < 4; ++r) {
            s1[r] = red16(s1[r]); s2[r] = red16(s2[r]);
            float mean = s1[r] * (1.f / 128.f);
            float var = s2[r] * (1.f / 128.f) - mean * mean;
            rstd[r] = rsqrtf(var + 1e-5f);
            mrr[r] = mean * rstd[r];
        }
        float p[4] = {0.f, 0.f, 0.f, 0.f};
#pragma unroll
        for (int nt = 0; nt < 8; ++nt) {
            float4 pp = *(const float4*)&par[(16 * nt + n) * 4];
#pragma unroll
            for (int r = 0; r < 4; ++r) {
                float z = fmaf(acc[nt][r], rstd[r], -mrr[r]);
                float y = fmaxf(fmaf(z, pp.y, pp.z), 0.f);
                p[r] = fmaf(y, pp.w, p[r]);
            }
        }
#pragma unroll
        for (int r = 0; r < 4; ++r) p[r] = red16(p[r]);
        if (n < 4) {
            float pv = p[n];
            A[(g << 4) + 4 * q + n] = 1.f / (1.f + expf(-(pv + b2s)));
        }
        g = gn;
    }
}

// ================= K1: cvt_all + count + cvt_w0 + precompute =================
__global__ __launch_bounds__(256) void prep_kernel(
    const float* __restrict__ emb, const float* __restrict__ xu,
    ushort* __restrict__ embB, ushort* __restrict__ xub,
    const int* __restrict__ dst0, const int* __restrict__ dst1,
    int* __restrict__ cnt0, int* __restrict__ cnt1,
    const float* __restrict__ llw0, const float* __restrict__ lrw0,
    ushort* __restrict__ Wb,
    const float* __restrict__ ow, const float* __restrict__ llw1,
    const float* __restrict__ lrw1, const float* __restrict__ llb1,
    const float* __restrict__ ob,
    float* __restrict__ v1, float* __restrict__ v2, float* __restrict__ cbuf)
{
    int b = blockIdx.x;
    int tid = threadIdx.x;
    if (b < PREP_CVT) {
        size_t i = ((size_t)b * 256 + tid) * 4;
        const size_t nEmb = (size_t)cV * cIN;
        const float* s; ushort* d; size_t j;
        if (i < nEmb) { s = emb; d = embB; j = i; }
        else { s = xu; d = xub; j = i - nEmb; }
        float4 v = *(const float4*)&s[j];
        *(uint2*)&d[j] = make_uint2(pkbf16(v.x, v.y), pkbf16(v.z, v.w));
    } else if (b < PREP_CNT) {
        int e = (b - PREP_CVT) * 256 + tid;
        if (e < cE0) atomicAdd(&cnt0[dst0[e]], 1);
        else atomicAdd(&cnt1[dst1[e - cE0]], 1);
    } else if (b < PREP_W0) {
        int i = ((b - PREP_CNT) * 256 + tid) * 2;
        int o = i >> 8, k = i & 255;
        float2 v = (k < 128) ? *(const float2*)&llw0[o * 128 + k]
                             : *(const float2*)&lrw0[o * 128 + (k - 128)];
        *(unsigned*)&Wb[i] = pkbf16(v.x, v.y);
    } else {
        int bb = b - PREP_W0;
        int wave = tid >> 6, lane = tid & 63;
        if (bb < 64) {
            int t = bb * 4 + wave;
            float s1 = 0.f, s2 = 0.f;
#pragma unroll
            for (int k = 0; k < 4; ++k) {
                int o = lane + 64 * k;
                float wo = ow[o];
                s1 = fmaf(wo, llw1[o * 256 + t], s1);
                s2 = fmaf(wo, lrw1[o * 256 + t], s2);
            }
            s1 = wave_sum(s1); s2 = wave_sum(s2);
            if (lane == 0) { v1[t] = s1; v2[t] = s2; }
        } else if (wave == 0) {
            float s = 0.f;
#pragma unroll
            for (int k = 0; k < 4; ++k) {
                int t = lane + 64 * k;
                s = fmaf(ow[t], llb1[t], s);
            }
            s = wave_sum(s);
            if (lane == 0) cbuf[0] = s + ob[0];
        }
    }
}

// ================= scan (unchanged) =================
__global__ __launch_bounds__(1024) void scan_kernel(const int* __restrict__ cnt0,
                                                    int* __restrict__ off0,
                                                    const int* __restrict__ cnt1,
                                                    int* __restrict__ off1)
{
    const int* cnt = blockIdx.x ? cnt1 : cnt0;
    int* off = blockIdx.x ? off1 : off0;
    int n = blockIdx.x ? cN2 : cN1;
    __shared__ int ps[1024];
    __shared__ int carrySh;
    int t = threadIdx.x;
    if (t == 0) carrySh = 0;
    __syncthreads();
    int ntile = (n + 16383) >> 14;
    for (int tl = 0; tl < ntile; ++tl) {
        int i0 = (tl << 14) + t * 16;
        int v[16];
        if (i0 + 16 <= n) {
            int4 a = *(const int4*)&cnt[i0];
            int4 bq = *(const int4*)&cnt[i0 + 4];
            int4 c = *(const int4*)&cnt[i0 + 8];
            int4 d = *(const int4*)&cnt[i0 + 12];
            v[0] = a.x; v[1] = a.y; v[2] = a.z; v[3] = a.w;
            v[4] = bq.x; v[5] = bq.y; v[6] = bq.z; v[7] = bq.w;
            v[8] = c.x; v[9] = c.y; v[10] = c.z; v[11] = c.w;
            v[12] = d.x; v[13] = d.y; v[14] = d.z; v[15] = d.w;
        } else {
#pragma unroll
            for (int k = 0; k < 16; ++k) v[k] = (i0 + k < n) ? cnt[i0 + k] : 0;
        }
        int s = 0;
#pragma unroll
        for (int k = 0; k < 16; ++k) s += v[k];
        ps[t] = s;
        __syncthreads();
        for (int d = 1; d < 1024; d <<= 1) {
            int x = (t >= d) ? ps[t - d] : 0;
            __syncthreads();
            ps[t] += x;
            __syncthreads();
        }
        int run = ps[t] - s + carrySh;
        if (i0 + 16 <= n) {
            int w[16];
#pragma unroll
            for (int k = 0; k < 16; ++k) { w[k] = run; run += v[k]; }
            *(int4*)&off[i0]      = make_int4(w[0], w[1], w[2], w[3]);
            *(int4*)&off[i0 + 4]  = make_int4(w[4], w[5], w[6], w[7]);
            *(int4*)&off[i0 + 8]  = make_int4(w[8], w[9], w[10], w[11]);
            *(int4*)&off[i0 + 12] = make_int4(w[12], w[13], w[14], w[15]);
        } else {
#pragma unroll
            for (int k = 0; k < 16; ++k)
                if (i0 + k < n) { off[i0 + k] = run; run += v[k]; }
        }
        __syncthreads();
        if (t == 1023) carrySh += ps[1023];
        __syncthreads();
    }
    if (t == 0) off[n] = carrySh;
}

// ================= K2: edge_mlp0 (interleaved) + scatter + embed =================
__global__ __launch_bounds__(256) void mid_kernel(
    const ushort* __restrict__ xub,
    const int* __restrict__ src0, const int* __restrict__ dst0,
    const float* __restrict__ w1, const float* __restrict__ b1v,
    const float* __restrict__ gv, const float* __restrict__ bnv,
    const float* __restrict__ w2, const float* __restrict__ b2,
    float* __restrict__ A0,
    const int* __restrict__ x, const ushort* __restrict__ embB,
    const float* __restrict__ g, const float* __restrict__ bvec,
    ushort* __restrict__ e0,
    const int* __restrict__ dst1,
    const int* __restrict__ off0, const int* __restrict__ off1,
    int* __restrict__ pos0, int* __restrict__ pos1,
    int* __restrict__ eid0, int* __restrict__ eid1)
{
    __shared__ ushort WtL[24 * 512];
    __shared__ float par[cLP * 4];
    int b = blockIdx.x;
    int tid = threadIdx.x;
    // role mapping: in [0, MID_MAIN) every 53rd block is an edge block (1024 total)
    int other_id;
    if (b < MID_MAIN) {
        int eb = b / 53;
        if (b - eb * 53 == 0) {
            int wid = eb * 4 + (tid >> 6);
            edge_mlp_body(WtL, par, tid, xub, cU, xub, cU, src0, dst0, cE0,
                          w1, b1v, gv, bnv, w2, b2, A0, wid, 4096);
            return;
        }
        other_id = b - eb - 1;
    } else {
        other_id = 53248 + (b - MID_MAIN);
    }
    if (other_id < 3750) {
        // scatter (both levels)
        int e = other_id * 256 + tid;
        if (e < cE0) {
            int d = dst0[e];
            int p = atomicAdd(&pos0[d], 1);
            eid0[off0[d] + p] = e;
        } else {
            int e1 = e - cE0;
            int d = dst1[e1];
            int p = atomicAdd(&pos1[d], 1);
            eid1[off1[d] + p] = e1;
        }
    } else {
        // embed
        int wave = tid >> 6, lane = tid & 63;
        int n = (other_id - 3750) * 4 + wave;
        const int* xr = x + (size_t)n * cL;
        int toks[cL];
#pragma unroll
        for (int t = 0; t < cL; ++t) toks[t] = xr[t];
        unsigned packed[cL];
#pragma unroll
        for (int t = 0; t < cL; ++t)
            packed[t] = *(const unsigned*)&embB[(size_t)toks[t] * cIN + 2 * lane];
        float ax = 0.f, ay = 0.f;
#pragma unroll
        for (int t = 0; t < cL; ++t) {
            unsigned p = (toks[t] != 0) ? packed[t] : 0u;
            float2 uv = unpk(p);
            ax += uv.x; ay += uv.y;
        }
        float s1 = wave_sum(ax + ay);
        float s2 = wave_sum(ax * ax + ay * ay);
        float mean = s1 * (1.f / cIN);
        float var = s2 * (1.f / cIN) - mean * mean;
        float rstd = rsqrtf(var + 1e-5f);
        float2 gv2 = *(const float2*)&g[2 * lane];
        float2 bv2 = *(const float2*)&bvec[2 * lane];
        float ox = fmaxf((ax - mean) * rstd * gv2.x + bv2.x, 0.f);
        float oy = fmaxf((ay - mean) * rstd * gv2.y + bv2.y, 0.f);
        *(unsigned*)&e0[(size_t)n * cIN + 2 * lane] = pkbf16(ox, oy);
    }
}

// ================= agg0 (unchanged) =================
__global__ __launch_bounds__(256) void agg0_kernel(
    const int* __restrict__ off, const int* __restrict__ eid,
    const int* __restrict__ src, const float* __restrict__ A,
    const ushort* __restrict__ e0, const ushort* __restrict__ xub,
    ushort* __restrict__ aggn, ushort* __restrict__ h1b)
{
    int wave = threadIdx.x >> 6, lane = threadIdx.x & 63;
    int i = blockIdx.x * 4 + wave;
    if (i >= cN1) return;
    int s0 = off[i], s1 = off[i + 1];
    bool feat = lane < 32;
    int col = feat ? (4 * lane) : (4 * (lane & 7));
    const ushort* base = feat ? e0 : xub;
    int stride = feat ? cIN : cU;
    float ax = 0.f, ay = 0.f, az = 0.f, aw = 0.f, accA = 0.f;
    int idx = s0;
    for (; idx + 8 <= s1; idx += 8) {
        int ee[8]; float av[8]; int ss[8]; ushort4 vv[8];
#pragma unroll
        for (int t = 0; t < 8; ++t) ee[t] = eid[idx + t];
#pragma unroll
        for (int t = 0; t < 8; ++t) { av[t] = A[ee[t]]; ss[t] = src[ee[t]]; }
#pragma unroll
        for (int t = 0; t < 8; ++t) vv[t] = *(const ushort4*)&base[(size_t)ss[t] * stride + col];
#pragma unroll
        for (int t = 0; t < 8; ++t) {
            float w = feat ? av[t] : 1.f;
            ax = fmaf(w, b2f(vv[t].x), ax); ay = fmaf(w, b2f(vv[t].y), ay);
            az = fmaf(w, b2f(vv[t].z), az); aw = fmaf(w, b2f(vv[t].w), aw);
            accA += av[t];
        }
    }
    for (; idx + 4 <= s1; idx += 4) {
        int ee[4]; float av[4]; int ss[4]; ushort4 vv[4];
#pragma unroll
        for (int t = 0; t < 4; ++t) ee[t] = eid[idx + t];
#pragma unroll
        for (int t = 0; t < 4; ++t) { av[t] = A[ee[t]]; ss[t] = src[ee[t]]; }
#pragma unroll
        for (int t = 0; t < 4; ++t) vv[t] = *(const ushort4*)&base[(size_t)ss[t] * stride + col];
#pragma unroll
        for (int t = 0; t < 4; ++t) {
            float w = feat ? av[t] : 1.f;
            ax = fmaf(w, b2f(vv[t].x), ax); ay = fmaf(w, b2f(vv[t].y), ay);
            az = fmaf(w, b2f(vv[t].z), az); aw = fmaf(w, b2f(vv[t].w), aw);
            accA += av[t];
        }
    }
    for (; idx < s1; ++idx) {
        int e = eid[idx];
        float a = A[e];
        int s = src[e];
        ushort4 v = *(const ushort4*)&base[(size_t)s * stride + col];
        float w = feat ? a : 1.f;
        ax = fmaf(w, b2f(v.x), ax); ay = fmaf(w, b2f(v.y), ay);
        az = fmaf(w, b2f(v.z), az); aw = fmaf(w, b2f(v.w), aw);
        accA += a;
    }
    if (feat) {
        float r = (accA > 0.f) ? (1.f / accA) : 0.f;
        unsigned o0 = pkbf16(ax * r, ay * r), o1 = pkbf16(az * r, aw * r);
        *(uint2*)&aggn[(size_t)i * cIN + col] = make_uint2(o0, o1);
    } else if (lane < 40) {
        unsigned o0 = pkbf16(ax, ay), o1 = pkbf16(az, aw);
        *(uint2*)&h1b[(size_t)i * 288 + 256 + col] = make_uint2(o0, o1);
    }
}

// ================= K4: linear0 + edge_mlp1 (interleaved) =================
__global__ __launch_bounds__(256) void tail_kernel(
    const ushort* __restrict__ aggn, const ushort* __restrict__ e0,
    const ushort* __restrict__ Wb, const float* __restrict__ bias,
    ushort* __restrict__ h1b,
    const int* __restrict__ src1, const int* __restrict__ dst1,
    const float* __restrict__ w1, const float* __restrict__ b1v,
    const float* __restrict__ gv, const float* __restrict__ bnv,
    const float* __restrict__ w2, const float* __restrict__ b2,
    float* __restrict__ A1)
{
    __shared__ ushort WtL[24 * 512];
    __shared__ float par[cLP * 4];
    int b = blockIdx.x;
    int tid = threadIdx.x;
    // roles: b<1024: odd -> edge (512), even -> linear (512); b>=1024: linear (272)
    bool isEdge = (b < 1024) && (b & 1);
    if (isEdge) {
        int eb = b >> 1;
        int wid = eb * 4 + (tid >> 6);
        edge_mlp_body(WtL, par, tid, h1b + 256, 288, h1b + 256, 288, src1, dst1, cE1,
                      w1, b1v, gv, bnv, w2, b2, A1, wid, 2048);
        return;
    }
    int lb = (b < 1024) ? (b >> 1) : (512 + (b - 1024));   // 784 linear blocks
    int w = tid >> 6, lane = tid & 63;
    int n = lane & 15, q = lane >> 4;
    short8 Bf[4][8];
    float bia[4];
#pragma unroll
    for (int t = 0; t < 4; ++t) {
        int col = 64 * w + 16 * t + n;
        bia[t] = bias[col];
#pragma unroll
        for (int kc = 0; kc < 8; ++kc)
            Bf[t][kc] = *(const short8*)&Wb[(size_t)col * 256 + kc * 32 + 8 * q];
    }
    for (int g = lb; g < cN1 / 16; g += 784) {
        int m0 = g * 16;
        int row = m0 + n;
        short8 Af[8];
#pragma unroll
        for (int kc = 0; kc < 4; ++kc)
            Af[kc] = *(const short8*)&aggn[(size_t)row * cIN + kc * 32 + 8 * q];
#pragma unroll
        for (int kc = 0; kc < 4; ++kc)
            Af[4 + kc] = *(const short8*)&e0[(size_t)row * cIN + kc * 32 + 8 * q];
#pragma unroll
        for (int t = 0; t < 4; ++t) {
            floatx4 acc = {0.f, 0.f, 0.f, 0.f};
#pragma unroll
            for (int kc = 0; kc < 8; ++kc)
                acc = __builtin_amdgcn_mfma_f32_16x16x32_bf16(Af[kc], Bf[t][kc], acc, 0, 0, 0);
            int col = 64 * w + 16 * t + n;
#pragma unroll
            for (int r = 0; r < 4; ++r) {
                int m = m0 + 4 * q + r;
                h1b[(size_t)m * 288 + col] = bf16_rne(fmaxf(acc[r] + bia[t], 0.f));
            }
        }
    }
}

// ================= agg1 + final projection (unchanged) =================
__global__ __launch_bounds__(256) void agg1_final_kernel(
    const int* __restrict__ off, const int* __restrict__ eid,
    const int* __restrict__ src, const float* __restrict__ A,
    const ushort* __restrict__ h1b, const float* __restrict__ v1,
    const float* __restrict__ v2, const float* __restrict__ cbuf,
    float* __restrict__ out)
{
    int wave = threadIdx.x >> 6, lane = threadIdx.x & 63;
    int n = blockIdx.x * 4 + wave;
    if (n >= cN2) return;
    int s0 = off[n], s1 = off[n + 1];
    float ax = 0.f, ay = 0.f, az = 0.f, aw = 0.f, accA = 0.f;
    int idx = s0;
    for (; idx + 8 <= s1; idx += 8) {
        int ee[8]; float av[8]; int ss[8]; ushort4 vv[8];
#pragma unroll
        for (int t = 0; t < 8; ++t) ee[t] = eid[idx + t];
#pragma unroll
        for (int t = 0; t < 8; ++t) { av[t] = A[ee[t]]; ss[t] = src[ee[t]]; }
#pragma unroll
        for (int t = 0; t < 8; ++t) vv[t] = *(const ushort4*)&h1b[(size_t)ss[t] * 288 + 4 * lane];
#pragma unroll
        for (int t = 0; t < 8; ++t) {
            ax = fmaf(av[t], b2f(vv[t].x), ax); ay = fmaf(av[t], b2f(vv[t].y), ay);
            az = fmaf(av[t], b2f(vv[t].z), az); aw = fmaf(av[t], b2f(vv[t].w), aw);
            accA += av[t];
        }
    }
    for (; idx + 4 <= s1; idx += 4) {
        int ee[4]; float av[4]; int ss[4]; ushort4 vv[4];
#pragma unroll
        for (int t = 0; t < 4; ++t) ee[t] = eid[idx + t];
#pragma unroll
        for (int t = 0; t < 4; ++t) { av[t] = A[ee[t]]; ss[t] = src[ee[t]]; }
#pragma unroll
        for (int t = 0; t < 4; ++t) vv[t] = *(const ushort4*)&h1b[(size_t)ss[t] * 288 + 4 * lane];
#pragma unroll
        for (int t = 0; t < 4; ++t) {
            ax = fmaf(av[t], b2f(vv[t].x), ax); ay = fmaf(av[t], b2f(vv[t].y), ay);
            az = fmaf(av[t], b2f(vv[t].z), az); aw = fmaf(av[t], b2f(vv[t].w), aw);
            accA += av[t];
        }
    }
    for (; idx < s1; ++idx) {
        int e = eid[idx];
        float a = A[e];
        int s = src[e];
        ushort4 v = *(const ushort4*)&h1b[(size_t)s * 288 + 4 * lane];
        ax = fmaf(a, b2f(v.x), ax); ay = fmaf(a, b2f(v.y), ay);
        az = fmaf(a, b2f(v.z), az); aw = fmaf(a, b2f(v.w), aw);
        accA += a;
    }
    float r = (accA > 0.f) ? (1.f / accA) : 0.f;
    ushort4 t4 = *(const ushort4*)&h1b[(size_t)n * 288 + 4 * lane];
    float4 w1v = *(const float4*)&v1[4 * lane];
    float4 w2v = *(const float4*)&v2[4 * lane];
    float p = r * (ax * w1v.x + ay * w1v.y + az * w1v.z + aw * w1v.w)
            + b2f(t4.x) * w2v.x + b2f(t4.y) * w2v.y
            + b2f(t4.z) * w2v.z + b2f(t4.w) * w2v.w;
    p = wave_sum(p);
    if (lane == 0) out[n] = p + cbuf[0];
}

extern "C" void kernel_launch(void* const* d_in, const int* in_sizes, int n_in,
                              void* d_out, int out_size, void* d_ws, size_t ws_size,
                              hipStream_t stream)
{
    const int*   x     = (const int*)d_in[0];
    const float* xu    = (const float*)d_in[1];
    const int*   src0  = (const int*)d_in[2];
    const int*   dst0  = (const int*)d_in[3];
    const int*   src1  = (const int*)d_in[4];
    const int*   dst1  = (const int*)d_in[5];
    const float* emb   = (const float*)d_in[6];
    const float* ln_g  = (const float*)d_in[7];
    const float* ln_b  = (const float*)d_in[8];
    const float* lp_w1 = (const float*)d_in[9];
    const float* lp_b1 = (const float*)d_in[10];
    const float* lp_g  = (const float*)d_in[11];
    const float* lp_bn = (const float*)d_in[12];
    const float* lp_w2 = (const float*)d_in[13];
    const float* lp_b2 = (const float*)d_in[14];
    const float* ll_w0 = (const float*)d_in[15];
    const float* ll_b0 = (const float*)d_in[16];
    const float* lr_w0 = (const float*)d_in[17];
    const float* ll_w1 = (const float*)d_in[18];
    const float* ll_b1 = (const float*)d_in[19];
    const float* lr_w1 = (const float*)d_in[20];
    const float* out_w = (const float*)d_in[21];
    const float* out_b = (const float*)d_in[22];
    float* out = (float*)d_out;

    char* ws = (char*)d_ws;
    size_t off = 0;
    auto alloc = [&](size_t bytes) -> void* {
        void* p = ws + off;
        off = (off + bytes + 255) & ~(size_t)255;
        return p;
    };
    ushort* embB = (ushort*)alloc((size_t)cV * cIN * 2);
    ushort* xub  = (ushort*)alloc((size_t)cN0 * cU * 2);
    ushort* e0   = (ushort*)alloc((size_t)cN0 * cIN * 2);
    ushort* aggn = (ushort*)alloc((size_t)cN1 * cIN * 2);
    ushort* h1b  = (ushort*)alloc((size_t)cN1 * 288 * 2);
    float* A0    = (float*)alloc((size_t)cE0 * 4);
    float* A1    = (float*)alloc((size_t)cE1 * 4);
    ushort* Wb   = (ushort*)alloc((size_t)256 * 256 * 2);
    float* v1    = (float*)alloc(256 * 4);
    float* v2    = (float*)alloc(256 * 4);
    float* cbuf  = (float*)alloc(64);
    char* zbase  = ws + off;
    int* cnt0    = (int*)alloc((size_t)cN1 * 4);
    int* pos0    = (int*)alloc((size_t)cN1 * 4);
    int* cnt1    = (int*)alloc((size_t)cN2 * 4);
    int* pos1    = (int*)alloc((size_t)cN2 * 4);
    size_t zlen  = (size_t)((ws + off) - zbase);
    int* off0    = (int*)alloc((size_t)(cN1 + 1) * 4);
    int* off1    = (int*)alloc((size_t)(cN2 + 1) * 4);
    int* eid0    = (int*)alloc((size_t)cE0 * 4);
    int* eid1    = (int*)alloc((size_t)cE1 * 4);

    hipMemsetAsync(zbase, 0, zlen, stream);

    prep_kernel<<<PREP_TOT, 256, 0, stream>>>(emb, xu, embB, xub, dst0, dst1, cnt0, cnt1,
                                              ll_w0, lr_w0, Wb, out_w, ll_w1, lr_w1,
                                              ll_b1, out_b, v1, v2, cbuf);

    scan_kernel<<<2, 1024, 0, stream>>>(cnt0, off0, cnt1, off1);

    mid_kernel<<<MID_TOT, 256, 0, stream>>>(xub, src0, dst0,
                                            lp_w1, lp_b1, lp_g, lp_bn, lp_w2, lp_b2, A0,
                                            x, embB, ln_g, ln_b, e0,
                                            dst1, off0, off1, pos0, pos1, eid0, eid1);

    agg0_kernel<<<(cN1 + 3) / 4, 256, 0, stream>>>(off0, eid0, src0, A0, e0, xub, aggn, h1b);

    tail_kernel<<<TAIL_TOT, 256, 0, stream>>>(aggn, e0, Wb, ll_b0, h1b,
                                              src1, dst1,
                                              lp_w1, lp_b1, lp_g, lp_bn, lp_w2, lp_b2, A1);

    agg1_final_kernel<<<(cN2 + 3) / 4, 256, 0, stream>>>(off1, eid1, src1, A1, h1b, v1, v2, cbuf, out);
}

// Round 12
// 551.084 us; speedup vs baseline: 1.1584x; 1.1584x over previous
//
#include <hip/hip_runtime.h>
#include <hip/hip_bf16.h>
#include <math.h>

#define cN0 200000
#define cN1 50000
#define cN2 10000
#define cL  10
#define cE0 800000
#define cE1 160000
#define cV  100000
#define cIN 128
#define cH  256
#define cU  32
#define cLP 128

// prep-grid layout
#define PREP_CVT   18750              // (cV*cIN + cN0*cU)/1024
#define PREP_CNT   22500              // + (cE0+cE1)/256 = 3750
#define PREP_W0    22628              // + 128
#define PREP_TOT   22693              // + 65

typedef __attribute__((ext_vector_type(8))) short short8;
typedef __attribute__((ext_vector_type(4))) float floatx4;

__device__ __forceinline__ float wave_sum(float v) {
#pragma unroll
    for (int m = 1; m < 64; m <<= 1) v += __shfl_xor(v, m);
    return v;
}

__device__ __forceinline__ float red16(float v) {
    v += __shfl_xor(v, 1); v += __shfl_xor(v, 2);
    v += __shfl_xor(v, 4); v += __shfl_xor(v, 8);
    return v;
}

__device__ __forceinline__ unsigned short bf16_rne(float f) {
    union { float f; unsigned u; } c; c.f = f;
    unsigned r = (c.u + 0x7FFFu + ((c.u >> 16) & 1u)) >> 16;
    return (unsigned short)r;
}

__device__ __forceinline__ float b2f(unsigned short u) {
    union { unsigned u; float f; } c; c.u = ((unsigned)u) << 16;
    return c.f;
}

__device__ __forceinline__ unsigned pkbf16(float a, float b) {
    union { __hip_bfloat162 h; unsigned u; } c;
    c.h = __float22bfloat162_rn(make_float2(a, b));
    return c.u;
}

__device__ __forceinline__ float2 unpk(unsigned p) {
    union { unsigned u; float f; } lo, hi;
    lo.u = p << 16; hi.u = p & 0xFFFF0000u;
    return make_float2(lo.f, hi.f);
}

// ================= K1: cvt_all + count + cvt_w0 + precompute (all lightweight) ======
__global__ __launch_bounds__(256) void prep_kernel(
    const float* __restrict__ emb, const float* __restrict__ xu,
    ushort* __restrict__ embB, ushort* __restrict__ xub,
    const int* __restrict__ dst0, const int* __restrict__ dst1,
    int* __restrict__ cnt0, int* __restrict__ cnt1,
    const float* __restrict__ llw0, const float* __restrict__ lrw0,
    ushort* __restrict__ Wb,
    const float* __restrict__ ow, const float* __restrict__ llw1,
    const float* __restrict__ lrw1, const float* __restrict__ llb1,
    const float* __restrict__ ob,
    float* __restrict__ v1, float* __restrict__ v2, float* __restrict__ cbuf)
{
    int b = blockIdx.x;
    int tid = threadIdx.x;
    if (b < PREP_CVT) {
        size_t i = ((size_t)b * 256 + tid) * 4;
        const size_t nEmb = (size_t)cV * cIN;
        const float* s; ushort* d; size_t j;
        if (i < nEmb) { s = emb; d = embB; j = i; }
        else { s = xu; d = xub; j = i - nEmb; }
        float4 v = *(const float4*)&s[j];
        *(uint2*)&d[j] = make_uint2(pkbf16(v.x, v.y), pkbf16(v.z, v.w));
    } else if (b < PREP_CNT) {
        int e = (b - PREP_CVT) * 256 + tid;
        if (e < cE0) atomicAdd(&cnt0[dst0[e]], 1);
        else atomicAdd(&cnt1[dst1[e - cE0]], 1);
    } else if (b < PREP_W0) {
        int i = ((b - PREP_CNT) * 256 + tid) * 2;
        int o = i >> 8, k = i & 255;
        float2 v = (k < 128) ? *(const float2*)&llw0[o * 128 + k]
                             : *(const float2*)&lrw0[o * 128 + (k - 128)];
        *(unsigned*)&Wb[i] = pkbf16(v.x, v.y);
    } else {
        int bb = b - PREP_W0;
        int wave = tid >> 6, lane = tid & 63;
        if (bb < 64) {
            int t = bb * 4 + wave;
            float s1 = 0.f, s2 = 0.f;
#pragma unroll
            for (int k = 0; k < 4; ++k) {
                int o = lane + 64 * k;
                float wo = ow[o];
                s1 = fmaf(wo, llw1[o * 256 + t], s1);
                s2 = fmaf(wo, lrw1[o * 256 + t], s2);
            }
            s1 = wave_sum(s1); s2 = wave_sum(s2);
            if (lane == 0) { v1[t] = s1; v2[t] = s2; }
        } else if (wave == 0) {
            float s = 0.f;
#pragma unroll
            for (int k = 0; k < 4; ++k) {
                int t = lane + 64 * k;
                s = fmaf(ow[t], llb1[t], s);
            }
            s = wave_sum(s);
            if (lane == 0) cbuf[0] = s + ob[0];
        }
    }
}

// ================= embedding + LN + relu -> e0 bf16 =================
__global__ __launch_bounds__(256) void embed_kernel(
    const int* __restrict__ x, const ushort* __restrict__ embB,
    const float* __restrict__ g, const float* __restrict__ b,
    ushort* __restrict__ e0)
{
    int wave = threadIdx.x >> 6, lane = threadIdx.x & 63;
    int n = blockIdx.x * 4 + wave;
    const int* xr = x + (size_t)n * cL;
    int toks[cL];
#pragma unroll
    for (int t = 0; t < cL; ++t) toks[t] = xr[t];
    unsigned packed[cL];
#pragma unroll
    for (int t = 0; t < cL; ++t)
        packed[t] = *(const unsigned*)&embB[(size_t)toks[t] * cIN + 2 * lane];
    float ax = 0.f, ay = 0.f;
#pragma unroll
    for (int t = 0; t < cL; ++t) {
        unsigned p = (toks[t] != 0) ? packed[t] : 0u;
        float2 uv = unpk(p);
        ax += uv.x; ay += uv.y;
    }
    float s1 = wave_sum(ax + ay);
    float s2 = wave_sum(ax * ax + ay * ay);
    float mean = s1 * (1.f / cIN);
    float var = s2 * (1.f / cIN) - mean * mean;
    float rstd = rsqrtf(var + 1e-5f);
    float2 gv = *(const float2*)&g[2 * lane];
    float2 bv = *(const float2*)&b[2 * lane];
    float ox = fmaxf((ax - mean) * rstd * gv.x + bv.x, 0.f);
    float oy = fmaxf((ay - mean) * rstd * gv.y + bv.y, 0.f);
    *(unsigned*)&e0[(size_t)n * cIN + 2 * lane] = pkbf16(ox, oy);
}

// ================= coalesced tiled scan =================
__global__ __launch_bounds__(1024) void scan_kernel(const int* __restrict__ cnt0,
                                                    int* __restrict__ off0,
                                                    const int* __restrict__ cnt1,
                                                    int* __restrict__ off1)
{
    const int* cnt = blockIdx.x ? cnt1 : cnt0;
    int* off = blockIdx.x ? off1 : off0;
    int n = blockIdx.x ? cN2 : cN1;
    __shared__ int ps[1024];
    __shared__ int carrySh;
    int t = threadIdx.x;
    if (t == 0) carrySh = 0;
    __syncthreads();
    int ntile = (n + 16383) >> 14;
    for (int tl = 0; tl < ntile; ++tl) {
        int i0 = (tl << 14) + t * 16;
        int v[16];
        if (i0 + 16 <= n) {
            int4 a = *(const int4*)&cnt[i0];
            int4 bq = *(const int4*)&cnt[i0 + 4];
            int4 c = *(const int4*)&cnt[i0 + 8];
            int4 d = *(const int4*)&cnt[i0 + 12];
            v[0] = a.x; v[1] = a.y; v[2] = a.z; v[3] = a.w;
            v[4] = bq.x; v[5] = bq.y; v[6] = bq.z; v[7] = bq.w;
            v[8] = c.x; v[9] = c.y; v[10] = c.z; v[11] = c.w;
            v[12] = d.x; v[13] = d.y; v[14] = d.z; v[15] = d.w;
        } else {
#pragma unroll
            for (int k = 0; k < 16; ++k) v[k] = (i0 + k < n) ? cnt[i0 + k] : 0;
        }
        int s = 0;
#pragma unroll
        for (int k = 0; k < 16; ++k) s += v[k];
        ps[t] = s;
        __syncthreads();
        for (int d = 1; d < 1024; d <<= 1) {
            int x = (t >= d) ? ps[t - d] : 0;
            __syncthreads();
            ps[t] += x;
            __syncthreads();
        }
        int run = ps[t] - s + carrySh;
        if (i0 + 16 <= n) {
            int w[16];
#pragma unroll
            for (int k = 0; k < 16; ++k) { w[k] = run; run += v[k]; }
            *(int4*)&off[i0]      = make_int4(w[0], w[1], w[2], w[3]);
            *(int4*)&off[i0 + 4]  = make_int4(w[4], w[5], w[6], w[7]);
            *(int4*)&off[i0 + 8]  = make_int4(w[8], w[9], w[10], w[11]);
            *(int4*)&off[i0 + 12] = make_int4(w[12], w[13], w[14], w[15]);
        } else {
#pragma unroll
            for (int k = 0; k < 16; ++k)
                if (i0 + k < n) { off[i0 + k] = run; run += v[k]; }
        }
        __syncthreads();
        if (t == 1023) carrySh += ps[1023];
        __syncthreads();
    }
    if (t == 0) off[n] = carrySh;
}

// ================= fused scatter over both levels =================
__global__ void scatter_kernel(const int* __restrict__ dst0, const int* __restrict__ dst1,
                               const int* __restrict__ off0, const int* __restrict__ off1,
                               int* __restrict__ pos0, int* __restrict__ pos1,
                               int* __restrict__ eid0, int* __restrict__ eid1)
{
    int e = blockIdx.x * 256 + threadIdx.x;
    if (e < cE0) {
        int d = dst0[e];
        int p = atomicAdd(&pos0[d], 1);
        eid0[off0[d] + p] = e;
    } else {
        int e1 = e - cE0;
        if (e1 < cE1) {
            int d = dst1[e1];
            int p = atomicAdd(&pos1[d], 1);
            eid1[off1[d] + p] = e1;
        }
    }
}

// ================= edge MLP via MFMA bf16; weights in LDS, natural occupancy ========
__global__ __launch_bounds__(256) void edge_mlp_mfma_kernel(
    const ushort* __restrict__ uni, int stride_i,
    const ushort* __restrict__ unj, int stride_j,
    const int* __restrict__ src, const int* __restrict__ dst, int E,
    const float* __restrict__ w1, const float* __restrict__ b1v,
    const float* __restrict__ gv, const float* __restrict__ bnv,
    const float* __restrict__ w2, const float* __restrict__ b2,
    float* __restrict__ A)
{
    __shared__ ushort WtL[24 * 512];
    __shared__ float par[cLP * 4];
    int tid = threadIdx.x;
    int lane = tid & 63;
    int n = lane & 15, q = lane >> 4;
    if (tid < cLP) {
        par[tid * 4 + 0] = b1v[tid];
        par[tid * 4 + 1] = gv[tid];
        par[tid * 4 + 2] = bnv[tid];
        par[tid * 4 + 3] = w2[tid];
    }
    if (tid < 64) {
#pragma unroll
        for (int nt = 0; nt < 8; ++nt) {
#pragma unroll
            for (int c = 0; c < 3; ++c) {
                const float* p = &w1[(size_t)(16 * nt + n) * 96 + 32 * c + 8 * q];
                float4 v0 = *(const float4*)p;
                float4 v1 = *(const float4*)(p + 4);
                unsigned* dstw = (unsigned*)&WtL[(nt * 3 + c) * 512 + lane * 8];
                dstw[0] = pkbf16(v0.x, v0.y);
                dstw[1] = pkbf16(v0.z, v0.w);
                dstw[2] = pkbf16(v1.x, v1.y);
                dstw[3] = pkbf16(v1.z, v1.w);
            }
        }
    }
    __syncthreads();
    float b2s = b2[0];

    int wid = blockIdx.x * 4 + (tid >> 6);
    int nw = gridDim.x * 4;
    int ngroups = E >> 4;

    int g = wid;
    uint4 iv = {0, 0, 0, 0}, jv = {0, 0, 0, 0};
    if (g < ngroups) {
        int e = (g << 4) + n;
        int di = dst[e], si = src[e];
        iv = *(const uint4*)&uni[(size_t)di * stride_i + 8 * q];
        jv = *(const uint4*)&unj[(size_t)si * stride_j + 8 * q];
    }
    while (g < ngroups) {
        int gn = g + nw;
        int din = 0, sin = 0;
        if (gn < ngroups) {
            int e2 = (gn << 4) + n;
            din = dst[e2]; sin = src[e2];
        }
        union { short8 s; unsigned u[4]; } a0, a1, a2;
        {
            unsigned iw[4] = {iv.x, iv.y, iv.z, iv.w};
            unsigned jw[4] = {jv.x, jv.y, jv.z, jv.w};
#pragma unroll
            for (int d = 0; d < 4; ++d) {
                float2 u = unpk(iw[d]);
                float2 v = unpk(jw[d]);
                a0.u[d] = pkbf16(fabsf(u.x - v.x), fabsf(u.y - v.y));
                a1.u[d] = pkbf16(u.x + v.x, u.y + v.y);
                a2.u[d] = pkbf16(u.x * v.x, u.y * v.y);
            }
        }
        if (gn < ngroups) {
            iv = *(const uint4*)&uni[(size_t)din * stride_i + 8 * q];
            jv = *(const uint4*)&unj[(size_t)sin * stride_j + 8 * q];
        }
        floatx4 acc[8];
#pragma unroll
        for (int nt = 0; nt < 8; ++nt) acc[nt] = (floatx4){0.f, 0.f, 0.f, 0.f};
#pragma unroll
        for (int nt = 0; nt < 8; ++nt) {
            short8 b0 = *(const short8*)&WtL[(nt * 3 + 0) * 512 + lane * 8];
            short8 b1 = *(const short8*)&WtL[(nt * 3 + 1) * 512 + lane * 8];
            short8 b2w = *(const short8*)&WtL[(nt * 3 + 2) * 512 + lane * 8];
            acc[nt] = __builtin_amdgcn_mfma_f32_16x16x32_bf16(a0.s, b0, acc[nt], 0, 0, 0);
            acc[nt] = __builtin_amdgcn_mfma_f32_16x16x32_bf16(a1.s, b1, acc[nt], 0, 0, 0);
            acc[nt] = __builtin_amdgcn_mfma_f32_16x16x32_bf16(a2.s, b2w, acc[nt], 0, 0, 0);
        }
        float s1[4] = {0.f, 0.f, 0.f, 0.f}, s2[4] = {0.f, 0.f, 0.f, 0.f};
#pragma unroll
        for (int nt = 0; nt < 8; ++nt) {
            float4 pp = *(const float4*)&par[(16 * nt + n) * 4];
#pragma unroll
            for (int r = 0; r < 4; ++r) {
                float h = acc[nt][r] + pp.x;
                acc[nt][r] = h;
                s1[r] += h; s2[r] = fmaf(h, h, s2[r]);
            }
        }
        float rstd[4], mrr[4];
#pragma unroll
        for (int r = 0; r < 4; ++r) {
            s1[r] = red16(s1[r]); s2[r] = red16(s2[r]);
            float mean = s1[r] * (1.f / 128.f);
            float var = s2[r] * (1.f / 128.f) - mean * mean;
            rstd[r] = rsqrtf(var + 1e-5f);
            mrr[r] = mean * rstd[r];
        }
        float p[4] = {0.f, 0.f, 0.f, 0.f};
#pragma unroll
        for (int nt = 0; nt < 8; ++nt) {
            float4 pp = *(const float4*)&par[(16 * nt + n) * 4];
#pragma unroll
            for (int r = 0; r < 4; ++r) {
                float z = fmaf(acc[nt][r], rstd[r], -mrr[r]);
                float y = fmaxf(fmaf(z, pp.y, pp.z), 0.f);
                p[r] = fmaf(y, pp.w, p[r]);
            }
        }
#pragma unroll
        for (int r = 0; r < 4; ++r) p[r] = red16(p[r]);
        if (n < 4) {
            float pv = p[n];
            A[(g << 4) + 4 * q + n] = 1.f / (1.f + expf(-(pv + b2s)));
        }
        g = gn;
    }
}

// ================= conv0 aggregation: 8/4-deep MLP unrolled gather =================
__global__ __launch_bounds__(256) void agg0_kernel(
    const int* __restrict__ off, const int* __restrict__ eid,
    const int* __restrict__ src, const float* __restrict__ A,
    const ushort* __restrict__ e0, const ushort* __restrict__ xub,
    ushort* __restrict__ aggn, ushort* __restrict__ h1b)
{
    int wave = threadIdx.x >> 6, lane = threadIdx.x & 63;
    int i = blockIdx.x * 4 + wave;
    if (i >= cN1) return;
    int s0 = off[i], s1 = off[i + 1];
    bool feat = lane < 32;
    int col = feat ? (4 * lane) : (4 * (lane & 7));
    const ushort* base = feat ? e0 : xub;
    int stride = feat ? cIN : cU;
    float ax = 0.f, ay = 0.f, az = 0.f, aw = 0.f, accA = 0.f;
    int idx = s0;
    for (; idx + 8 <= s1; idx += 8) {
        int ee[8]; float av[8]; int ss[8]; ushort4 vv[8];
#pragma unroll
        for (int t = 0; t < 8; ++t) ee[t] = eid[idx + t];
#pragma unroll
        for (int t = 0; t < 8; ++t) { av[t] = A[ee[t]]; ss[t] = src[ee[t]]; }
#pragma unroll
        for (int t = 0; t < 8; ++t) vv[t] = *(const ushort4*)&base[(size_t)ss[t] * stride + col];
#pragma unroll
        for (int t = 0; t < 8; ++t) {
            float w = feat ? av[t] : 1.f;
            ax = fmaf(w, b2f(vv[t].x), ax); ay = fmaf(w, b2f(vv[t].y), ay);
            az = fmaf(w, b2f(vv[t].z), az); aw = fmaf(w, b2f(vv[t].w), aw);
            accA += av[t];
        }
    }
    for (; idx + 4 <= s1; idx += 4) {
        int ee[4]; float av[4]; int ss[4]; ushort4 vv[4];
#pragma unroll
        for (int t = 0; t < 4; ++t) ee[t] = eid[idx + t];
#pragma unroll
        for (int t = 0; t < 4; ++t) { av[t] = A[ee[t]]; ss[t] = src[ee[t]]; }
#pragma unroll
        for (int t = 0; t < 4; ++t) vv[t] = *(const ushort4*)&base[(size_t)ss[t] * stride + col];
#pragma unroll
        for (int t = 0; t < 4; ++t) {
            float w = feat ? av[t] : 1.f;
            ax = fmaf(w, b2f(vv[t].x), ax); ay = fmaf(w, b2f(vv[t].y), ay);
            az = fmaf(w, b2f(vv[t].z), az); aw = fmaf(w, b2f(vv[t].w), aw);
            accA += av[t];
        }
    }
    for (; idx < s1; ++idx) {
        int e = eid[idx];
        float a = A[e];
        int s = src[e];
        ushort4 v = *(const ushort4*)&base[(size_t)s * stride + col];
        float w = feat ? a : 1.f;
        ax = fmaf(w, b2f(v.x), ax); ay = fmaf(w, b2f(v.y), ay);
        az = fmaf(w, b2f(v.z), az); aw = fmaf(w, b2f(v.w), aw);
        accA += a;
    }
    if (feat) {
        float r = (accA > 0.f) ? (1.f / accA) : 0.f;
        unsigned o0 = pkbf16(ax * r, ay * r), o1 = pkbf16(az * r, aw * r);
        *(uint2*)&aggn[(size_t)i * cIN + col] = make_uint2(o0, o1);
    } else if (lane < 40) {
        unsigned o0 = pkbf16(ax, ay), o1 = pkbf16(az, aw);
        *(uint2*)&h1b[(size_t)i * 288 + 256 + col] = make_uint2(o0, o1);
    }
}

// ================= linear0 via MFMA =================
__global__ __launch_bounds__(256) void linear0_mfma_kernel(
    const ushort* __restrict__ aggn, const ushort* __restrict__ e0,
    const ushort* __restrict__ Wb, const float* __restrict__ bias,
    ushort* __restrict__ h1b)
{
    int tid = threadIdx.x;
    int w = tid >> 6, lane = tid & 63;
    int n = lane & 15, q = lane >> 4;
    short8 Bf[4][8];
    float bia[4];
#pragma unroll
    for (int t = 0; t < 4; ++t) {
        int col = 64 * w + 16 * t + n;
        bia[t] = bias[col];
#pragma unroll
        for (int kc = 0; kc < 8; ++kc)
            Bf[t][kc] = *(const short8*)&Wb[(size_t)col * 256 + kc * 32 + 8 * q];
    }
    for (int g = blockIdx.x; g < cN1 / 16; g += gridDim.x) {
        int m0 = g * 16;
        int row = m0 + n;
        short8 Af[8];
#pragma unroll
        for (int kc = 0; kc < 4; ++kc)
            Af[kc] = *(const short8*)&aggn[(size_t)row * cIN + kc * 32 + 8 * q];
#pragma unroll
        for (int kc = 0; kc < 4; ++kc)
            Af[4 + kc] = *(const short8*)&e0[(size_t)row * cIN + kc * 32 + 8 * q];
#pragma unroll
        for (int t = 0; t < 4; ++t) {
            floatx4 acc = {0.f, 0.f, 0.f, 0.f};
#pragma unroll
            for (int kc = 0; kc < 8; ++kc)
                acc = __builtin_amdgcn_mfma_f32_16x16x32_bf16(Af[kc], Bf[t][kc], acc, 0, 0, 0);
            int col = 64 * w + 16 * t + n;
#pragma unroll
            for (int r = 0; r < 4; ++r) {
                int m = m0 + 4 * q + r;
                h1b[(size_t)m * 288 + col] = bf16_rne(fmaxf(acc[r] + bia[t], 0.f));
            }
        }
    }
}

// ================= agg1 + final projection =================
__global__ __launch_bounds__(256) void agg1_final_kernel(
    const int* __restrict__ off, const int* __restrict__ eid,
    const int* __restrict__ src, const float* __restrict__ A,
    const ushort* __restrict__ h1b, const float* __restrict__ v1,
    const float* __restrict__ v2, const float* __restrict__ cbuf,
    float* __restrict__ out)
{
    int wave = threadIdx.x >> 6, lane = threadIdx.x & 63;
    int n = blockIdx.x * 4 + wave;
    if (n >= cN2) return;
    int s0 = off[n], s1 = off[n + 1];
    float ax = 0.f, ay = 0.f, az = 0.f, aw = 0.f, accA = 0.f;
    int idx = s0;
    for (; idx + 8 <= s1; idx += 8) {
        int ee[8]; float av[8]; int ss[8]; ushort4 vv[8];
#pragma unroll
        for (int t = 0; t < 8; ++t) ee[t] = eid[idx + t];
#pragma unroll
        for (int t = 0; t < 8; ++t) { av[t] = A[ee[t]]; ss[t] = src[ee[t]]; }
#pragma unroll
        for (int t = 0; t < 8; ++t) vv[t] = *(const ushort4*)&h1b[(size_t)ss[t] * 288 + 4 * lane];
#pragma unroll
        for (int t = 0; t < 8; ++t) {
            ax = fmaf(av[t], b2f(vv[t].x), ax); ay = fmaf(av[t], b2f(vv[t].y), ay);
            az = fmaf(av[t], b2f(vv[t].z), az); aw = fmaf(av[t], b2f(vv[t].w), aw);
            accA += av[t];
        }
    }
    for (; idx + 4 <= s1; idx += 4) {
        int ee[4]; float av[4]; int ss[4]; ushort4 vv[4];
#pragma unroll
        for (int t = 0; t < 4; ++t) ee[t] = eid[idx + t];
#pragma unroll
        for (int t = 0; t < 4; ++t) { av[t] = A[ee[t]]; ss[t] = src[ee[t]]; }
#pragma unroll
        for (int t = 0; t < 4; ++t) vv[t] = *(const ushort4*)&h1b[(size_t)ss[t] * 288 + 4 * lane];
#pragma unroll
        for (int t = 0; t < 4; ++t) {
            ax = fmaf(av[t], b2f(vv[t].x), ax); ay = fmaf(av[t], b2f(vv[t].y), ay);
            az = fmaf(av[t], b2f(vv[t].z), az); aw = fmaf(av[t], b2f(vv[t].w), aw);
            accA += av[t];
        }
    }
    for (; idx < s1; ++idx) {
        int e = eid[idx];
        float a = A[e];
        int s = src[e];
        ushort4 v = *(const ushort4*)&h1b[(size_t)s * 288 + 4 * lane];
        ax = fmaf(a, b2f(v.x), ax); ay = fmaf(a, b2f(v.y), ay);
        az = fmaf(a, b2f(v.z), az); aw = fmaf(a, b2f(v.w), aw);
        accA += a;
    }
    float r = (accA > 0.f) ? (1.f / accA) : 0.f;
    ushort4 t4 = *(const ushort4*)&h1b[(size_t)n * 288 + 4 * lane];
    float4 w1v = *(const float4*)&v1[4 * lane];
    float4 w2v = *(const float4*)&v2[4 * lane];
    float p = r * (ax * w1v.x + ay * w1v.y + az * w1v.z + aw * w1v.w)
            + b2f(t4.x) * w2v.x + b2f(t4.y) * w2v.y
            + b2f(t4.z) * w2v.z + b2f(t4.w) * w2v.w;
    p = wave_sum(p);
    if (lane == 0) out[n] = p + cbuf[0];
}

extern "C" void kernel_launch(void* const* d_in, const int* in_sizes, int n_in,
                              void* d_out, int out_size, void* d_ws, size_t ws_size,
                              hipStream_t stream)
{
    const int*   x     = (const int*)d_in[0];
    const float* xu    = (const float*)d_in[1];
    const int*   src0  = (const int*)d_in[2];
    const int*   dst0  = (const int*)d_in[3];
    const int*   src1  = (const int*)d_in[4];
    const int*   dst1  = (const int*)d_in[5];
    const float* emb   = (const float*)d_in[6];
    const float* ln_g  = (const float*)d_in[7];
    const float* ln_b  = (const float*)d_in[8];
    const float* lp_w1 = (const float*)d_in[9];
    const float* lp_b1 = (const float*)d_in[10];
    const float* lp_g  = (const float*)d_in[11];
    const float* lp_bn = (const float*)d_in[12];
    const float* lp_w2 = (const float*)d_in[13];
    const float* lp_b2 = (const float*)d_in[14];
    const float* ll_w0 = (const float*)d_in[15];
    const float* ll_b0 = (const float*)d_in[16];
    const float* lr_w0 = (const float*)d_in[17];
    const float* ll_w1 = (const float*)d_in[18];
    const float* ll_b1 = (const float*)d_in[19];
    const float* lr_w1 = (const float*)d_in[20];
    const float* out_w = (const float*)d_in[21];
    const float* out_b = (const float*)d_in[22];
    float* out = (float*)d_out;

    char* ws = (char*)d_ws;
    size_t off = 0;
    auto alloc = [&](size_t bytes) -> void* {
        void* p = ws + off;
        off = (off + bytes + 255) & ~(size_t)255;
        return p;
    };
    ushort* embB = (ushort*)alloc((size_t)cV * cIN * 2);
    ushort* xub  = (ushort*)alloc((size_t)cN0 * cU * 2);
    ushort* e0   = (ushort*)alloc((size_t)cN0 * cIN * 2);
    ushort* aggn = (ushort*)alloc((size_t)cN1 * cIN * 2);
    ushort* h1b  = (ushort*)alloc((size_t)cN1 * 288 * 2);
    float* A0    = (float*)alloc((size_t)cE0 * 4);
    float* A1    = (float*)alloc((size_t)cE1 * 4);
    ushort* Wb   = (ushort*)alloc((size_t)256 * 256 * 2);
    float* v1    = (float*)alloc(256 * 4);
    float* v2    = (float*)alloc(256 * 4);
    float* cbuf  = (float*)alloc(64);
    char* zbase  = ws + off;
    int* cnt0    = (int*)alloc((size_t)cN1 * 4);
    int* pos0    = (int*)alloc((size_t)cN1 * 4);
    int* cnt1    = (int*)alloc((size_t)cN2 * 4);
    int* pos1    = (int*)alloc((size_t)cN2 * 4);
    size_t zlen  = (size_t)((ws + off) - zbase);
    int* off0    = (int*)alloc((size_t)(cN1 + 1) * 4);
    int* off1    = (int*)alloc((size_t)(cN2 + 1) * 4);
    int* eid0    = (int*)alloc((size_t)cE0 * 4);
    int* eid1    = (int*)alloc((size_t)cE1 * 4);

    hipMemsetAsync(zbase, 0, zlen, stream);

    prep_kernel<<<PREP_TOT, 256, 0, stream>>>(emb, xu, embB, xub, dst0, dst1, cnt0, cnt1,
                                              ll_w0, lr_w0, Wb, out_w, ll_w1, lr_w1,
                                              ll_b1, out_b, v1, v2, cbuf);

    embed_kernel<<<cN0 / 4, 256, 0, stream>>>(x, embB, ln_g, ln_b, e0);

    scan_kernel<<<2, 1024, 0, stream>>>(cnt0, off0, cnt1, off1);
    scatter_kernel<<<(cE0 + cE1 + 255) / 256, 256, 0, stream>>>(dst0, dst1, off0, off1,
                                                                pos0, pos1, eid0, eid1);

    edge_mlp_mfma_kernel<<<1024, 256, 0, stream>>>(xub, cU, xub, cU, src0, dst0, cE0,
                                                   lp_w1, lp_b1, lp_g, lp_bn, lp_w2, lp_b2, A0);

    agg0_kernel<<<(cN1 + 3) / 4, 256, 0, stream>>>(off0, eid0, src0, A0, e0, xub, aggn, h1b);

    linear0_mfma_kernel<<<784, 256, 0, stream>>>(aggn, e0, Wb, ll_b0, h1b);

    edge_mlp_mfma_kernel<<<512, 256, 0, stream>>>(h1b + 256, 288, h1b + 256, 288, src1, dst1, cE1,
                                                  lp_w1, lp_b1, lp_g, lp_bn, lp_w2, lp_b2, A1);

    agg1_final_kernel<<<(cN2 + 3) / 4, 256, 0, stream>>>(off1, eid1, src1, A1, h1b, v1, v2, cbuf, out);
}